// Round 4
// baseline (74.403 us; speedup 1.0000x reference)
//
#include <hip/hip_runtime.h>

#define TABLE_MASK 0x7FFFFu
#define RES 512.0f
#define HPI2 2654435761u
#define HPI3 805459861u

typedef float vf2 __attribute__((ext_vector_type(2)));
typedef float vf4 __attribute__((ext_vector_type(4)));

__device__ __forceinline__ void point_setup(float xs, float ys, float zs,
                                            unsigned idx[8], float w[8]) {
    xs *= RES; ys *= RES; zs *= RES;
    float xf = floorf(xs), yf = floorf(ys), zf = floorf(zs);

    float wx0 = 1.0f - (xs - xf);
    float wx1 = 1.0f - fabsf(xs - (xf + 1.0f));
    float wy0 = 1.0f - (ys - yf);
    float wy1 = 1.0f - fabsf(ys - (yf + 1.0f));
    float wz0 = 1.0f - (zs - zf);
    float wz1 = 1.0f - fabsf(zs - (zf + 1.0f));

    unsigned cx = (unsigned)(int)xf;
    unsigned cy = (unsigned)(int)yf;
    unsigned cz = (unsigned)(int)zf;
    unsigned hx0 = cx;            // * PI1 (=1)
    unsigned hx1 = cx + 1u;
    unsigned hy0 = cy * HPI2;
    unsigned hy1 = (cy + 1u) * HPI2;
    unsigned hz0 = cz * HPI3;
    unsigned hz1 = (cz + 1u) * HPI3;

    idx[0] = (hx0 ^ hy0 ^ hz0) & TABLE_MASK;
    idx[1] = (hx0 ^ hy0 ^ hz1) & TABLE_MASK;
    idx[2] = (hx0 ^ hy1 ^ hz0) & TABLE_MASK;
    idx[3] = (hx0 ^ hy1 ^ hz1) & TABLE_MASK;
    idx[4] = (hx1 ^ hy0 ^ hz0) & TABLE_MASK;
    idx[5] = (hx1 ^ hy0 ^ hz1) & TABLE_MASK;
    idx[6] = (hx1 ^ hy1 ^ hz0) & TABLE_MASK;
    idx[7] = (hx1 ^ hy1 ^ hz1) & TABLE_MASK;

    w[0] = wx0 * wy0 * wz0;
    w[1] = wx0 * wy0 * wz1;
    w[2] = wx0 * wy1 * wz0;
    w[3] = wx0 * wy1 * wz1;
    w[4] = wx1 * wy0 * wz0;
    w[5] = wx1 * wy0 * wz1;
    w[6] = wx1 * wy1 * wz0;
    w[7] = wx1 * wy1 * wz1;
}

__global__ __launch_bounds__(256) void ingp_gather2_kernel(
    const float* __restrict__ x,
    const float2* __restrict__ table,
    float* __restrict__ out,
    int npair, int odd_n)
{
    int i = blockIdx.x * blockDim.x + threadIdx.x;

    if (i < npair) {
        // two points per thread: 6 floats = three aligned 8B nt-loads
        const vf2* xv = (const vf2*)x;
        vf2 a = __builtin_nontemporal_load(xv + 3 * i + 0);
        vf2 b = __builtin_nontemporal_load(xv + 3 * i + 1);
        vf2 c = __builtin_nontemporal_load(xv + 3 * i + 2);

        unsigned ia[8], ib[8];
        float wa[8], wb[8];
        point_setup(a.x, a.y, b.x, ia, wa);
        point_setup(b.y, c.x, c.y, ib, wb);

        // issue all 16 gathers before any consumption (MLP)
        float2 fa[8], fb[8];
        #pragma unroll
        for (int k = 0; k < 8; ++k) fa[k] = table[ia[k]];
        #pragma unroll
        for (int k = 0; k < 8; ++k) fb[k] = table[ib[k]];

        float ox0 = 0.f, oy0 = 0.f, ox1 = 0.f, oy1 = 0.f;
        #pragma unroll
        for (int k = 0; k < 8; ++k) { ox0 += fa[k].x * wa[k]; oy0 += fa[k].y * wa[k]; }
        #pragma unroll
        for (int k = 0; k < 8; ++k) { ox1 += fb[k].x * wb[k]; oy1 += fb[k].y * wb[k]; }

        vf4 o;
        o.x = ox0; o.y = oy0; o.z = ox1; o.w = oy1;
        __builtin_nontemporal_store(o, (vf4*)out + i);
    }

    // odd-N tail: one designated thread handles the last point
    if (odd_n && i == npair) {
        int p = 2 * npair;
        unsigned idx[8];
        float w[8];
        point_setup(x[3 * p], x[3 * p + 1], x[3 * p + 2], idx, w);
        float ox = 0.f, oy = 0.f;
        #pragma unroll
        for (int k = 0; k < 8; ++k) {
            float2 f = table[idx[k]];
            ox += f.x * w[k];
            oy += f.y * w[k];
        }
        out[2 * p]     = ox;
        out[2 * p + 1] = oy;
    }
}

extern "C" void kernel_launch(void* const* d_in, const int* in_sizes, int n_in,
                              void* d_out, int out_size, void* d_ws, size_t ws_size,
                              hipStream_t stream) {
    const float*  x     = (const float*)d_in[0];
    const float2* table = (const float2*)d_in[1];
    int n = in_sizes[0] / 3;          // [N,3] flat
    int npair = n / 2;
    int odd_n = n & 1;

    int threads = npair + odd_n;
    int block = 256;
    int grid = (threads + block - 1) / block;
    ingp_gather2_kernel<<<grid, block, 0, stream>>>(
        x, table, (float*)d_out, npair, odd_n);
}

// Round 5
// 65.884 us; speedup vs baseline: 1.1293x; 1.1293x over previous
//
#include <hip/hip_runtime.h>

#define TABLE_MASK 0x7FFFFu
#define RES 512.0f
#define HPI2 2654435761u
#define HPI3 805459861u

typedef float vf2 __attribute__((ext_vector_type(2)));

__global__ __launch_bounds__(256) void ingp_gather1_kernel(
    const float* __restrict__ x,
    const float2* __restrict__ table,
    float* __restrict__ out,
    int n)
{
    int i = blockIdx.x * blockDim.x + threadIdx.x;
    if (i >= n) return;

    // 1 point/thread: max wave-level request concurrency (2M threads)
    float xs = __builtin_nontemporal_load(x + 3 * i + 0) * RES;
    float ys = __builtin_nontemporal_load(x + 3 * i + 1) * RES;
    float zs = __builtin_nontemporal_load(x + 3 * i + 2) * RES;

    float xf = floorf(xs), yf = floorf(ys), zf = floorf(zs);

    // indices first — issue all 8 gathers before any weight math
    unsigned cx = (unsigned)(int)xf;
    unsigned cy = (unsigned)(int)yf;
    unsigned cz = (unsigned)(int)zf;
    unsigned hx0 = cx;            // * PI1 (=1)
    unsigned hx1 = cx + 1u;
    unsigned hy0 = cy * HPI2;
    unsigned hy1 = (cy + 1u) * HPI2;
    unsigned hz0 = cz * HPI3;
    unsigned hz1 = (cz + 1u) * HPI3;

    float2 f0 = table[(hx0 ^ hy0 ^ hz0) & TABLE_MASK];
    float2 f1 = table[(hx0 ^ hy0 ^ hz1) & TABLE_MASK];
    float2 f2 = table[(hx0 ^ hy1 ^ hz0) & TABLE_MASK];
    float2 f3 = table[(hx0 ^ hy1 ^ hz1) & TABLE_MASK];
    float2 f4 = table[(hx1 ^ hy0 ^ hz0) & TABLE_MASK];
    float2 f5 = table[(hx1 ^ hy0 ^ hz1) & TABLE_MASK];
    float2 f6 = table[(hx1 ^ hy1 ^ hz0) & TABLE_MASK];
    float2 f7 = table[(hx1 ^ hy1 ^ hz1) & TABLE_MASK];

    // weights (overlaps with gather latency)
    float wx0 = 1.0f - (xs - xf);
    float wx1 = 1.0f - fabsf(xs - (xf + 1.0f));
    float wy0 = 1.0f - (ys - yf);
    float wy1 = 1.0f - fabsf(ys - (yf + 1.0f));
    float wz0 = 1.0f - (zs - zf);
    float wz1 = 1.0f - fabsf(zs - (zf + 1.0f));

    float w0 = wx0 * wy0 * wz0;
    float w1 = wx0 * wy0 * wz1;
    float w2 = wx0 * wy1 * wz0;
    float w3 = wx0 * wy1 * wz1;
    float w4 = wx1 * wy0 * wz0;
    float w5 = wx1 * wy0 * wz1;
    float w6 = wx1 * wy1 * wz0;
    float w7 = wx1 * wy1 * wz1;

    float ox = f0.x * w0 + f1.x * w1 + f2.x * w2 + f3.x * w3
             + f4.x * w4 + f5.x * w5 + f6.x * w6 + f7.x * w7;
    float oy = f0.y * w0 + f1.y * w1 + f2.y * w2 + f3.y * w3
             + f4.y * w4 + f5.y * w5 + f6.y * w6 + f7.y * w7;

    vf2 o; o.x = ox; o.y = oy;
    __builtin_nontemporal_store(o, (vf2*)out + i);
}

extern "C" void kernel_launch(void* const* d_in, const int* in_sizes, int n_in,
                              void* d_out, int out_size, void* d_ws, size_t ws_size,
                              hipStream_t stream) {
    const float*  x     = (const float*)d_in[0];
    const float2* table = (const float2*)d_in[1];
    int n = in_sizes[0] / 3;   // [N,3] flat

    int block = 256;
    int grid = (n + block - 1) / block;
    ingp_gather1_kernel<<<grid, block, 0, stream>>>(x, table, (float*)d_out, n);
}